// Round 3
// baseline (711.667 us; speedup 1.0000x reference)
//
#include <hip/hip_runtime.h>
#include <hip/hip_bf16.h>

// Problem constants
// B=8, H=W=64, N=4096, VA_IN=256, VB_IN=128, VC_IN=64, VOUT=128, R0=2, R1=4
//
// MEGA-KERNEL: the pipeline is perfectly tile-decomposable by 64 tokens:
//   embA(64 tok) -> 2x attend_b(32 tok) -> 8x attend_c(8 tok) -> final(64 tok)
// One block per 64-token tile runs all phases over one shared LDS buffer.
// Intermediates (gates/proj/Sa/Sb/Sc) stay in the workspace but are written
// and re-read by the SAME CU within microseconds -> L1/L2 hits, not HBM.
//
// attend LDS: 128 cols x 128 shorts (256B row), XOR-swizzled
//   byte ^= (col&7)<<4  -- involution applied on EVERY access (store+load).
// embA/final LDS: pitch 260 shorts (130 words == 2 mod 32 -> free 2-way).

typedef __attribute__((ext_vector_type(8))) short bhalf8;
typedef __attribute__((ext_vector_type(4))) float f32x4;

__device__ __forceinline__ unsigned short f2b(float f) {
  union { float f; unsigned u; } v; v.f = f;
  unsigned r = v.u + 0x7FFFu + ((v.u >> 16) & 1u);  // RNE
  return (unsigned short)(r >> 16);
}
__device__ __forceinline__ float b2f(unsigned short h) {
  union { unsigned u; float f; } v; v.u = ((unsigned)h) << 16;
  return v.f;
}
__device__ __forceinline__ unsigned pk2(float a, float b) {
  return (unsigned)f2b(a) | ((unsigned)f2b(b) << 16);
}

// ---------------------------------------------------------------------------
// Prep: convert all weights to bf16; compute wv = W2^T . Wrw[128:]
// ---------------------------------------------------------------------------
__global__ __launch_bounds__(256) void k_prep_all(
    const float* __restrict__ Wa1, const float* __restrict__ Wa2,
    const float* __restrict__ Wgb, const float* __restrict__ Wgc,
    const float* __restrict__ Wb1, const float* __restrict__ Wb2,
    const float* __restrict__ Wc1, const float* __restrict__ Wc2,
    const float* __restrict__ Wr1, const float* __restrict__ Wr2,
    const float* __restrict__ Wab, const float* __restrict__ Wac,
    unsigned short* __restrict__ Wa1b, unsigned short* __restrict__ Wa2b,
    unsigned short* __restrict__ Wgbb, unsigned short* __restrict__ Wgcb,
    unsigned short* __restrict__ W1b_b, unsigned short* __restrict__ W2b_b,
    unsigned short* __restrict__ W1b_c, unsigned short* __restrict__ W2b_c,
    unsigned short* __restrict__ Wr1b, unsigned short* __restrict__ Wr2b,
    float* __restrict__ wv_b, float* __restrict__ wv_c) {
  const float* srcs[10] = {Wa1, Wa2, Wgb, Wgc, Wb1, Wb2, Wc1, Wc2, Wr1, Wr2};
  unsigned short* dsts[10] = {Wa1b, Wa2b, Wgbb, Wgcb, W1b_b, W2b_b, W1b_c, W2b_c, Wr1b, Wr2b};
  const int sizes[10] = {32768, 16384, 32768, 32768, 16384, 16384, 8192, 16384, 98304, 65536};
  int gid = blockIdx.x * 256 + threadIdx.x;
  int stride = gridDim.x * 256;
#pragma unroll
  for (int s = 0; s < 10; ++s)
    for (int i = gid; i < sizes[s]; i += stride) dsts[s][i] = f2b(srcs[s][i]);
  if (blockIdx.x == 0) {
    int u = threadIdx.x;
    if (u < 128) {
      float s = 0.f;
      for (int c = 0; c < 128; ++c) s += Wab[128 + c] * Wb2[c * 128 + u];
      wv_b[u] = s;
    } else {
      int v = u - 128;
      float s = 0.f;
      for (int c = 0; c < 128; ++c) s += Wac[128 + c] * Wc2[c * 128 + v];
      wv_c[v] = s;
    }
  }
}

// ---------------------------------------------------------------------------
// MFMA attend body, fully wave-local, ZERO barriers (verbatim round-2 body).
// Each wave owns 32 unfold-columns = 32/P complete tokens.
// LDS: 128 cols x 256B, XOR-swizzled (col&7)<<4, uses first 32 KB of smem.
// ---------------------------------------------------------------------------
template <int R, int KIN>
__device__ __forceinline__ void attend_body(
    const float* __restrict__ vsrc,            // [B][KIN][64R][64R]
    const unsigned short* __restrict__ W1b,    // [128][KIN] bf16
    const unsigned short* __restrict__ W2b,    // [128][128] bf16
    const float* __restrict__ wv,              // [128] = W2^T . Wrw_p
    const float* __restrict__ proj,            // [B][4096]
    const unsigned short* __restrict__ gate,   // [B][4096][128] bf16
    unsigned short* __restrict__ outS,         // [B][4096][128] bf16
    unsigned short* smem, int blk) {
  constexpr int P = R * R;
  constexpr int T = 128 / P;   // tokens per block-pass
  constexpr int TW = 32 / P;   // tokens per wave
  constexpr int K1 = KIN / 32;
  constexpr int HR = 64 * R;
  constexpr int TILES = 4096 / T;

  const int u = threadIdx.x;
  const int b = blk / TILES;
  const int tile = blk % TILES;
  const int n0 = tile * T;
  const int h = n0 >> 6, w0 = n0 & 63;
  const size_t HRW = (size_t)HR * HR;
  const float* vb = vsrc + (size_t)b * KIN * HRW;

  const int wave = u >> 6, lane = u & 63, quad = lane >> 4, ln = lane & 15;
  const int tok0 = n0 + wave * TW;  // wave's first token (within image)

  // swizzled LDS address: row = col*256B, byte ^= (col&7)<<4 (involution)
  auto sa = [&](int col, int kshort) -> unsigned short* {
    unsigned byte = ((unsigned)col << 8) + ((unsigned)kshort << 1);
    byte ^= ((unsigned)(col & 7)) << 4;
    return (unsigned short*)((char*)smem + byte);
  };

  // ---- issue-early: proj + (R=4) gates, consumed at the very end ----
  const int mycol = wave * 32 + (lane >> 1);
  float mproj = proj[b * 4096 + n0 + mycol / P];
  unsigned gpre[TW <= 2 ? TW : 1];
  if constexpr (TW <= 2) {
#pragma unroll
    for (int t = 0; t < TW; ++t)
      gpre[t] = *(const unsigned*)(gate + ((size_t)b * 4096 + tok0 + t) * 128 + 2 * lane);
  }

  // ---- per-wave stage of own 32 cols (KIN ch) as bf16 [col][k] ----
#pragma unroll
  for (int j = 0; j < KIN / 4; ++j) {
    int idx = j * 64 + lane;
    int cloc = idx & 31;
    int kp = idx >> 5;  // [0, KIN/2)
    int col = wave * 32 + cloc;
    int t = col / P, r = col & (P - 1);
    int kh = r / R, kw = r & (R - 1);
    int hp = h * R + kh;
    int wp = (w0 + t) * R + kw;
    size_t base = (size_t)(2 * kp) * HRW + (size_t)hp * HR + wp;
    float f0 = vb[base];
    float f1 = vb[base + HRW];
    *(unsigned*)sa(col, 2 * kp) = pk2(f0, f1);
  }
  // no __syncthreads(): everything below is wave-local.

  // ---- layer 1: H = relu(W1 @ V) ----
  bhalf8 bf1[2][K1];
#pragma unroll
  for (int c2 = 0; c2 < 2; ++c2) {
    int col = wave * 32 + c2 * 16 + ln;
#pragma unroll
    for (int ks = 0; ks < K1; ++ks)
      bf1[c2][ks] = *(const bhalf8*)sa(col, ks * 32 + quad * 8);
  }
  f32x4 acc[8][2];
#pragma unroll
  for (int rt = 0; rt < 8; ++rt)
#pragma unroll
    for (int c2 = 0; c2 < 2; ++c2) acc[rt][c2] = (f32x4)(0.f);
#pragma unroll
  for (int rt = 0; rt < 8; ++rt) {
    bhalf8 af[K1];
#pragma unroll
    for (int ks = 0; ks < K1; ++ks)
      af[ks] = *(const bhalf8*)((const short*)W1b + (rt * 16 + ln) * KIN + ks * 32 + quad * 8);
#pragma unroll
    for (int c2 = 0; c2 < 2; ++c2)
#pragma unroll
      for (int ks = 0; ks < K1; ++ks)
        acc[rt][c2] = __builtin_amdgcn_mfma_f32_16x16x32_bf16(af[ks], bf1[c2][ks],
                                                              acc[rt][c2], 0, 0, 0);
  }
  // H overlay (own cols; V consumed into bf1)
#pragma unroll
  for (int rt = 0; rt < 8; ++rt)
#pragma unroll
    for (int c2 = 0; c2 < 2; ++c2) {
      int col = wave * 32 + c2 * 16 + ln;
      f32x4 v = acc[rt][c2];
      uint2 p;
      p.x = pk2(fmaxf(v.x, 0.f), fmaxf(v.y, 0.f));
      p.y = pk2(fmaxf(v.z, 0.f), fmaxf(v.w, 0.f));
      *(uint2*)sa(col, rt * 16 + quad * 4) = p;
    }

  // ---- logit: 2 lanes per col, 64 k each ----
  float lg;
  {
    int half = lane & 1;
    float s = 0.f;
#pragma unroll 8
    for (int k = 0; k < 64; k += 2) {
      unsigned pkv = *(const unsigned*)sa(mycol, half * 64 + k);
      s += wv[half * 64 + k] * b2f((unsigned short)pkv) +
           wv[half * 64 + k + 1] * b2f((unsigned short)(pkv >> 16));
    }
    s += __shfl_xor(s, 1, 64);
    lg = fmaxf(s + mproj, 0.f);  // lanes 2c,2c+1 both hold logit of col c
  }

  // ---- layer 2: E = W2 @ H ----
  bhalf8 bf2[2][4];
#pragma unroll
  for (int c2 = 0; c2 < 2; ++c2) {
    int col = wave * 32 + c2 * 16 + ln;
#pragma unroll
    for (int ks = 0; ks < 4; ++ks)
      bf2[c2][ks] = *(const bhalf8*)sa(col, ks * 32 + quad * 8);
  }
#pragma unroll
  for (int rt = 0; rt < 8; ++rt)
#pragma unroll
    for (int c2 = 0; c2 < 2; ++c2) acc[rt][c2] = (f32x4)(0.f);
#pragma unroll
  for (int rt = 0; rt < 8; ++rt) {
    bhalf8 af[4];
#pragma unroll
    for (int ks = 0; ks < 4; ++ks)
      af[ks] = *(const bhalf8*)((const short*)W2b + (rt * 16 + ln) * 128 + ks * 32 + quad * 8);
#pragma unroll
    for (int c2 = 0; c2 < 2; ++c2)
#pragma unroll
      for (int ks = 0; ks < 4; ++ks)
        acc[rt][c2] = __builtin_amdgcn_mfma_f32_16x16x32_bf16(af[ks], bf2[c2][ks],
                                                              acc[rt][c2], 0, 0, 0);
  }
  // E overlay (own cols; H consumed into bf2 + logit)
#pragma unroll
  for (int rt = 0; rt < 8; ++rt)
#pragma unroll
    for (int c2 = 0; c2 < 2; ++c2) {
      int col = wave * 32 + c2 * 16 + ln;
      f32x4 v = acc[rt][c2];
      uint2 p;
      p.x = pk2(v.x, v.y);
      p.y = pk2(v.z, v.w);
      *(uint2*)sa(col, rt * 16 + quad * 4) = p;
    }

  // ---- wave-parallel softmax over each token's P patch-cols ----
  float mx = lg;
  mx = fmaxf(mx, __shfl_xor(mx, 2, 64));
  mx = fmaxf(mx, __shfl_xor(mx, 4, 64));
  if constexpr (P == 16) {
    mx = fmaxf(mx, __shfl_xor(mx, 8, 64));
    mx = fmaxf(mx, __shfl_xor(mx, 16, 64));
  }
  float ex = expf(lg - mx);
  float sm = ex;
  sm += __shfl_xor(sm, 2, 64);
  sm += __shfl_xor(sm, 4, 64);
  if constexpr (P == 16) {
    sm += __shfl_xor(sm, 8, 64);
    sm += __shfl_xor(sm, 16, 64);
  }
  float wgt = ex / sm;  // weight of col (lane>>1), duplicated on lane pairs

  // ---- gated weighted sum + sigmoid -> token-major bf16 (own tokens) ----
#pragma unroll
  for (int t = 0; t < TW; ++t) {
    float s0 = 0.f, s1 = 0.f;
#pragma unroll
    for (int r = 0; r < P; ++r) {
      float w = __shfl(wgt, (t * P + r) * 2, 64);  // uniform src -> readlane
      unsigned pkv = *(const unsigned*)sa(wave * 32 + t * P + r, 2 * lane);
      s0 += w * b2f((unsigned short)pkv);
      s1 += w * b2f((unsigned short)(pkv >> 16));
    }
    size_t tok = (size_t)b * 4096 + tok0 + t;
    unsigned gk;
    if constexpr (TW <= 2) gk = gpre[t];
    else gk = *(const unsigned*)(gate + tok * 128 + 2 * lane);
    float v0 = s0 * b2f((unsigned short)gk);
    float v1 = s1 * b2f((unsigned short)(gk >> 16));
    *(unsigned*)(outS + tok * 128 + 2 * lane) =
        pk2(1.f / (1.f + expf(-v0)), 1.f / (1.f + expf(-v1)));
  }
}

// ---------------------------------------------------------------------------
// MEGA kernel: one block per 64-token tile runs the whole pipeline.
//   phase E: embA (verbatim round-2 body)  -> Sa, Gb, Gc, proj (L2-hot)
//   phase B: attend<2,128> x2 (32-tok sub-tiles) -> Sb
//   phase C: attend<4,64>  x8 ( 8-tok sub-tiles) -> Sc
//   phase F: final (verbatim round-2 body) reads Sb/Sc/Sa -> out
// Barriers only BETWEEN phases (shared LDS buffer reuse); each phase body is
// internally barrier-free and wave-local. 512 blocks -> all co-resident.
// ---------------------------------------------------------------------------
__global__ __launch_bounds__(256) void k_mega(
    const float* __restrict__ va, const float* __restrict__ vb2,
    const float* __restrict__ vc4,
    const unsigned short* __restrict__ Wa1b, const unsigned short* __restrict__ Wa2b,
    const unsigned short* __restrict__ Wgbb, const unsigned short* __restrict__ Wgcb,
    const float* __restrict__ Wab, const float* __restrict__ Wac,
    const unsigned short* __restrict__ W1b_b, const unsigned short* __restrict__ W2b_b,
    const unsigned short* __restrict__ W1b_c, const unsigned short* __restrict__ W2b_c,
    const unsigned short* __restrict__ Wr1b, const unsigned short* __restrict__ Wr2b,
    const float* __restrict__ wv_b, const float* __restrict__ wv_c,
    unsigned short* __restrict__ Sa, unsigned short* __restrict__ Gb,
    unsigned short* __restrict__ Gc, unsigned short* __restrict__ Sb,
    unsigned short* __restrict__ Sc,
    float* __restrict__ proj_ab, float* __restrict__ proj_ac,
    float* __restrict__ out) {
  constexpr int PX = 260;  // 130 words == 2 mod 32
  __shared__ unsigned short smem[64 * PX];  // 33.3 KB, reused by all phases
  __shared__ float wabl[128], wacl[128];
  const int u = threadIdx.x;
  const int b = blockIdx.x >> 6, tile64 = blockIdx.x & 63;
  const int n0g = tile64 * 64;
  const int wave = u >> 6, lane = u & 63, quad = lane >> 4, ln = lane & 15;

  // ================= phase E: embA =================
  {
    // every wave writes the same values (benign identical race); each wave
    // reads after its OWN writes -> in-wave ordering, no barrier needed.
    wabl[lane] = Wab[lane];
    wabl[lane + 64] = Wab[lane + 64];
    wacl[lane] = Wac[lane];
    wacl[lane + 64] = Wac[lane + 64];

    // per-wave stage of own 16 cols (256 ch) -> bf16 LDS [col][k]
    const float* xb = va + (size_t)b * 256 * 4096 + n0g;
#pragma unroll
    for (int j = 0; j < 32; ++j) {
      int idx = j * 64 + lane;
      int cloc = idx & 15;
      int kp = idx >> 4;  // [0,128)
      int col = wave * 16 + cloc;
      float f0 = xb[(size_t)(2 * kp) * 4096 + col];
      float f1 = xb[(size_t)(2 * kp + 1) * 4096 + col];
      *(unsigned*)(smem + col * PX + 2 * kp) = pk2(f0, f1);
    }
    // no barrier: all smem traffic below is wave-local.

    const int col = wave * 16 + ln;
    const size_t tok = (size_t)(b * 4096 + n0g + col);

    bhalf8 bx[8];
#pragma unroll
    for (int ks = 0; ks < 8; ++ks)
      bx[ks] = *(const bhalf8*)(smem + col * PX + ks * 32 + quad * 8);

    f32x4 acc[8];
    // H = relu(Wa1 @ X) -> overlay into smem (own cols; X consumed into bx)
#pragma unroll
    for (int rt = 0; rt < 8; ++rt) acc[rt] = (f32x4)(0.f);
#pragma unroll
    for (int rt = 0; rt < 8; ++rt)
#pragma unroll
      for (int ks = 0; ks < 8; ++ks) {
        bhalf8 af = *(const bhalf8*)((const short*)Wa1b + (rt * 16 + ln) * 256 + ks * 32 + quad * 8);
        acc[rt] = __builtin_amdgcn_mfma_f32_16x16x32_bf16(af, bx[ks], acc[rt], 0, 0, 0);
      }
#pragma unroll
    for (int rt = 0; rt < 8; ++rt) {
      f32x4 v = acc[rt];
      uint2 p;
      p.x = pk2(fmaxf(v.x, 0.f), fmaxf(v.y, 0.f));
      p.y = pk2(fmaxf(v.z, 0.f), fmaxf(v.w, 0.f));
      *(uint2*)(smem + col * PX + rt * 16 + quad * 4) = p;
    }

    // gate_b = 1/(1+exp(Wgb @ X))
#pragma unroll
    for (int rt = 0; rt < 8; ++rt) acc[rt] = (f32x4)(0.f);
#pragma unroll
    for (int rt = 0; rt < 8; ++rt)
#pragma unroll
      for (int ks = 0; ks < 8; ++ks) {
        bhalf8 af = *(const bhalf8*)((const short*)Wgbb + (rt * 16 + ln) * 256 + ks * 32 + quad * 8);
        acc[rt] = __builtin_amdgcn_mfma_f32_16x16x32_bf16(af, bx[ks], acc[rt], 0, 0, 0);
      }
#pragma unroll
    for (int rt = 0; rt < 8; ++rt) {
      f32x4 v = acc[rt];
      uint2 p;
      p.x = pk2(1.f / (1.f + expf(v.x)), 1.f / (1.f + expf(v.y)));
      p.y = pk2(1.f / (1.f + expf(v.z)), 1.f / (1.f + expf(v.w)));
      *(uint2*)(Gb + tok * 128 + rt * 16 + quad * 4) = p;
    }

    // gate_c
#pragma unroll
    for (int rt = 0; rt < 8; ++rt) acc[rt] = (f32x4)(0.f);
#pragma unroll
    for (int rt = 0; rt < 8; ++rt)
#pragma unroll
      for (int ks = 0; ks < 8; ++ks) {
        bhalf8 af = *(const bhalf8*)((const short*)Wgcb + (rt * 16 + ln) * 256 + ks * 32 + quad * 8);
        acc[rt] = __builtin_amdgcn_mfma_f32_16x16x32_bf16(af, bx[ks], acc[rt], 0, 0, 0);
      }
#pragma unroll
    for (int rt = 0; rt < 8; ++rt) {
      f32x4 v = acc[rt];
      uint2 p;
      p.x = pk2(1.f / (1.f + expf(v.x)), 1.f / (1.f + expf(v.y)));
      p.y = pk2(1.f / (1.f + expf(v.z)), 1.f / (1.f + expf(v.w)));
      *(uint2*)(Gc + tok * 128 + rt * 16 + quad * 4) = p;
    }

    // E = Wa2 @ H (wave-local)
    bhalf8 bh[4];
#pragma unroll
    for (int ks = 0; ks < 4; ++ks)
      bh[ks] = *(const bhalf8*)(smem + col * PX + ks * 32 + quad * 8);
#pragma unroll
    for (int rt = 0; rt < 8; ++rt) acc[rt] = (f32x4)(0.f);
#pragma unroll
    for (int rt = 0; rt < 8; ++rt)
#pragma unroll
      for (int ks = 0; ks < 4; ++ks) {
        bhalf8 af = *(const bhalf8*)((const short*)Wa2b + (rt * 16 + ln) * 128 + ks * 32 + quad * 8);
        acc[rt] = __builtin_amdgcn_mfma_f32_16x16x32_bf16(af, bh[ks], acc[rt], 0, 0, 0);
      }

    // proj + Sa = sigmoid(E)
    float pab = 0.f, pac = 0.f;
#pragma unroll
    for (int rt = 0; rt < 8; ++rt) {
      f32x4 v = acc[rt];
#pragma unroll
      for (int i = 0; i < 4; ++i) {
        float e = v[i];
        pab += wabl[rt * 16 + quad * 4 + i] * e;
        pac += wacl[rt * 16 + quad * 4 + i] * e;
      }
      uint2 p;
      p.x = pk2(1.f / (1.f + expf(-v.x)), 1.f / (1.f + expf(-v.y)));
      p.y = pk2(1.f / (1.f + expf(-v.z)), 1.f / (1.f + expf(-v.w)));
      *(uint2*)(Sa + tok * 128 + rt * 16 + quad * 4) = p;
    }
    pab += __shfl_xor(pab, 16, 64);
    pab += __shfl_xor(pab, 32, 64);
    pac += __shfl_xor(pac, 16, 64);
    pac += __shfl_xor(pac, 32, 64);
    if (lane < 16) {
      proj_ab[b * 4096 + n0g + col] = pab;
      proj_ac[b * 4096 + n0g + col] = pac;
    }
  }
  __syncthreads();  // phase E done (all global stores drained per-wave)

  // ================= phase B: attend R0=2 (2 x 32-token sub-tiles) =========
  for (int i = 0; i < 2; ++i) {
    attend_body<2, 128>(vb2, W1b_b, W2b_b, wv_b, proj_ab, Gb, Sb, smem,
                        b * 128 + (n0g >> 5) + i);
    __syncthreads();
  }

  // ================= phase C: attend R1=4 (8 x 8-token sub-tiles) ==========
  for (int i = 0; i < 8; ++i) {
    attend_body<4, 64>(vc4, W1b_c, W2b_c, wv_c, proj_ac, Gc, Sc, smem,
                       b * 512 + (n0g >> 3) + i);
    __syncthreads();
  }

  // ================= phase F: final =================
  {
    constexpr int PY = 260;
    const int col = wave * 16 + ln;
    const size_t tok = (size_t)(b * 4096 + n0g + col);

    bhalf8 bs[12];
#pragma unroll
    for (int ks = 0; ks < 12; ++ks) {
      const unsigned short* S = (ks < 4) ? Sb : ((ks < 8) ? Sc : Sa);
      bs[ks] = *(const bhalf8*)(S + tok * 128 + (ks & 3) * 32 + quad * 8);
    }

    f32x4 acc[16];
#pragma unroll
    for (int rt = 0; rt < 16; ++rt) acc[rt] = (f32x4)(0.f);
#pragma unroll
    for (int rt = 0; rt < 16; ++rt)
#pragma unroll
      for (int ks = 0; ks < 12; ++ks) {
        bhalf8 af = *(const bhalf8*)((const short*)Wr1b + (rt * 16 + ln) * 384 + ks * 32 + quad * 8);
        acc[rt] = __builtin_amdgcn_mfma_f32_16x16x32_bf16(af, bs[ks], acc[rt], 0, 0, 0);
      }
#pragma unroll
    for (int rt = 0; rt < 16; ++rt) {
      f32x4 v = acc[rt];
      uint2 p;
      p.x = pk2(fmaxf(v.x, 0.f), fmaxf(v.y, 0.f));
      p.y = pk2(fmaxf(v.z, 0.f), fmaxf(v.w, 0.f));
      *(uint2*)(smem + col * PY + rt * 16 + quad * 4) = p;
    }

    // wave-local: no barrier needed
    bhalf8 by[8];
#pragma unroll
    for (int ks = 0; ks < 8; ++ks)
      by[ks] = *(const bhalf8*)(smem + col * PY + ks * 32 + quad * 8);
#pragma unroll
    for (int rt = 0; rt < 16; ++rt) acc[rt] = (f32x4)(0.f);
#pragma unroll
    for (int rt = 0; rt < 16; ++rt)
#pragma unroll
      for (int ks = 0; ks < 8; ++ks) {
        bhalf8 af = *(const bhalf8*)((const short*)Wr2b + (rt * 16 + ln) * 256 + ks * 32 + quad * 8);
        acc[rt] = __builtin_amdgcn_mfma_f32_16x16x32_bf16(af, by[ks], acc[rt], 0, 0, 0);
      }
#pragma unroll
    for (int rt = 0; rt < 16; ++rt) {
      f32x4 v = acc[rt];
#pragma unroll
      for (int i = 0; i < 4; ++i)
        out[((size_t)(b * 256 + rt * 16 + quad * 4 + i)) * 4096 + n0g + col] = v[i];
    }
  }
}

extern "C" void kernel_launch(void* const* d_in, const int* in_sizes, int n_in,
                              void* d_out, int out_size, void* d_ws, size_t ws_size,
                              hipStream_t stream) {
  (void)in_sizes; (void)n_in; (void)out_size; (void)ws_size;
  const float* va  = (const float*)d_in[0];
  const float* vb  = (const float*)d_in[1];
  const float* vc  = (const float*)d_in[2];
  const float* Wa1 = (const float*)d_in[3];
  const float* Wa2 = (const float*)d_in[4];
  const float* Wgb = (const float*)d_in[5];
  const float* Wgc = (const float*)d_in[6];
  const float* Wb1 = (const float*)d_in[7];
  const float* Wb2 = (const float*)d_in[8];
  const float* Wc1 = (const float*)d_in[9];
  const float* Wc2 = (const float*)d_in[10];
  const float* Wab = (const float*)d_in[11];
  const float* Wac = (const float*)d_in[12];
  const float* Wr1 = (const float*)d_in[13];
  const float* Wr2 = (const float*)d_in[14];
  float* out = (float*)d_out;
  float* f = (float*)d_ws;

  const size_t SM = (size_t)8 * 4096 * 128 / 2;  // bf16 token-major array, in floats
  unsigned short* Sb = (unsigned short*)f; f += SM;
  unsigned short* Sc = (unsigned short*)f; f += SM;
  unsigned short* Sa = (unsigned short*)f; f += SM;
  unsigned short* Gb = (unsigned short*)f; f += SM;
  unsigned short* Gc = (unsigned short*)f; f += SM;
  float* proj_ab = f; f += 8 * 4096;
  float* proj_ac = f; f += 8 * 4096;
  float* wv_b = f; f += 128;
  float* wv_c = f; f += 128;
  unsigned short* Wa1b = (unsigned short*)f; f += 16384;
  unsigned short* Wa2b = (unsigned short*)f; f += 8192;
  unsigned short* Wgbb = (unsigned short*)f; f += 16384;
  unsigned short* Wgcb = (unsigned short*)f; f += 16384;
  unsigned short* W1b_b = (unsigned short*)f; f += 8192;
  unsigned short* W2b_b = (unsigned short*)f; f += 8192;
  unsigned short* W1b_c = (unsigned short*)f; f += 4096;
  unsigned short* W2b_c = (unsigned short*)f; f += 8192;
  unsigned short* Wr1b = (unsigned short*)f; f += 49152;
  unsigned short* Wr2b = (unsigned short*)f; f += 32768;

  dim3 blk(256);
  k_prep_all<<<120, blk, 0, stream>>>(Wa1, Wa2, Wgb, Wgc, Wb1, Wb2, Wc1, Wc2,
                                      Wr1, Wr2, Wab, Wac,
                                      Wa1b, Wa2b, Wgbb, Wgcb, W1b_b, W2b_b,
                                      W1b_c, W2b_c, Wr1b, Wr2b, wv_b, wv_c);
  k_mega<<<512, blk, 0, stream>>>(va, vb, vc,
                                  Wa1b, Wa2b, Wgbb, Wgcb, Wab, Wac,
                                  W1b_b, W2b_b, W1b_c, W2b_c, Wr1b, Wr2b,
                                  wv_b, wv_c,
                                  Sa, Gb, Gc, Sb, Sc, proj_ab, proj_ac, out);
}

// Round 4
// 599.174 us; speedup vs baseline: 1.1877x; 1.1877x over previous
//
#include <hip/hip_runtime.h>
#include <hip/hip_bf16.h>

// Problem constants
// B=8, H=W=64, N=4096, VA_IN=256, VB_IN=128, VC_IN=64, VOUT=128, R0=2, R1=4
//
// Round-2 structure (3 kernels + prep), plus:
//  - vectorized float4 staging in attend + embA (was scalar loads)
//  - logit computed as row 128 of an extended W2 (144x128) via one extra
//    MFMA rt-iteration; serial logit loop + wv global loads deleted
//  - softmax in MFMA output layout (quad0 lanes), wave-local, zero barriers
//
// attend LDS: 128 cols x 128 shorts (256B row), XOR-swizzled
//   byte ^= (col&7)<<4  -- involution applied on EVERY access (store+load).
// embA/final LDS: pitch 260 shorts (130 words == 2 mod 32 -> free 2-way).

typedef __attribute__((ext_vector_type(8))) short bhalf8;
typedef __attribute__((ext_vector_type(4))) float f32x4;

__device__ __forceinline__ unsigned short f2b(float f) {
  union { float f; unsigned u; } v; v.f = f;
  unsigned r = v.u + 0x7FFFu + ((v.u >> 16) & 1u);  // RNE
  return (unsigned short)(r >> 16);
}
__device__ __forceinline__ float b2f(unsigned short h) {
  union { unsigned u; float f; } v; v.u = ((unsigned)h) << 16;
  return v.f;
}
__device__ __forceinline__ unsigned pk2(float a, float b) {
  return (unsigned)f2b(a) | ((unsigned)f2b(b) << 16);
}

// ---------------------------------------------------------------------------
// Prep: convert all weights to bf16; W2ext row128 = bf16(W2^T . Wrw[128:]),
// rows 129..143 zero.
// ---------------------------------------------------------------------------
__global__ __launch_bounds__(256) void k_prep_all(
    const float* __restrict__ Wa1, const float* __restrict__ Wa2,
    const float* __restrict__ Wgb, const float* __restrict__ Wgc,
    const float* __restrict__ Wb1, const float* __restrict__ Wb2,
    const float* __restrict__ Wc1, const float* __restrict__ Wc2,
    const float* __restrict__ Wr1, const float* __restrict__ Wr2,
    const float* __restrict__ Wab, const float* __restrict__ Wac,
    unsigned short* __restrict__ Wa1b, unsigned short* __restrict__ Wa2b,
    unsigned short* __restrict__ Wgbb, unsigned short* __restrict__ Wgcb,
    unsigned short* __restrict__ W1b_b, unsigned short* __restrict__ W2b_b,
    unsigned short* __restrict__ W1b_c, unsigned short* __restrict__ W2b_c,
    unsigned short* __restrict__ Wr1b, unsigned short* __restrict__ Wr2b,
    float* __restrict__ wv_b, float* __restrict__ wv_c) {
  const float* srcs[10] = {Wa1, Wa2, Wgb, Wgc, Wb1, Wb2, Wc1, Wc2, Wr1, Wr2};
  unsigned short* dsts[10] = {Wa1b, Wa2b, Wgbb, Wgcb, W1b_b, W2b_b, W1b_c, W2b_c, Wr1b, Wr2b};
  const int sizes[10] = {32768, 16384, 32768, 32768, 16384, 16384, 8192, 16384, 98304, 65536};
  int gid = blockIdx.x * 256 + threadIdx.x;
  int stride = gridDim.x * 256;
#pragma unroll
  for (int s = 0; s < 10; ++s)
    for (int i = gid; i < sizes[s]; i += stride) dsts[s][i] = f2b(srcs[s][i]);
  if (blockIdx.x == 0) {
    int u = threadIdx.x;
    if (u < 128) {
      float s = 0.f;
      for (int c = 0; c < 128; ++c) s += Wab[128 + c] * Wb2[c * 128 + u];
      wv_b[u] = s;
      W2b_b[128 * 128 + u] = f2b(s);   // logit row of W2ext
    } else {
      int v = u - 128;
      float s = 0.f;
      for (int c = 0; c < 128; ++c) s += Wac[128 + c] * Wc2[c * 128 + v];
      wv_c[v] = s;
      W2b_c[128 * 128 + v] = f2b(s);
    }
  }
  if (blockIdx.x == 1) {
    for (int i = threadIdx.x; i < 15 * 128; i += 256) {
      W2b_b[129 * 128 + i] = 0;        // pad rows of W2ext
      W2b_c[129 * 128 + i] = 0;
    }
  }
}

// ---------------------------------------------------------------------------
// embA (MFMA), fully wave-local, ZERO barriers; float4-vectorized staging.
// ---------------------------------------------------------------------------
__global__ __launch_bounds__(256) void k_embA(
    const float* __restrict__ va,
    const unsigned short* __restrict__ Wa1b, const unsigned short* __restrict__ Wa2b,
    const unsigned short* __restrict__ Wgbb, const unsigned short* __restrict__ Wgcb,
    const float* __restrict__ Wab, const float* __restrict__ Wac,
    unsigned short* __restrict__ Sa, unsigned short* __restrict__ Gb,
    unsigned short* __restrict__ Gc,
    float* __restrict__ proj_ab, float* __restrict__ proj_ac) {
  constexpr int PX = 260;  // 130 words == 2 mod 32
  __shared__ unsigned short Xs[64 * PX];   // 33.3 KB (X, then H overlay)
  __shared__ float wabl[128], wacl[128];
  const int u = threadIdx.x;
  const int b = blockIdx.x >> 6, tile = blockIdx.x & 63;
  const int n0 = tile * 64;
  const int wave = u >> 6, lane = u & 63, quad = lane >> 4, ln = lane & 15;

  // benign identical-data race; each wave reads after its OWN writes.
  wabl[lane] = Wab[lane];
  wabl[lane + 64] = Wab[lane + 64];
  wacl[lane] = Wac[lane];
  wacl[lane + 64] = Wac[lane + 64];

  // ---- per-wave vectorized stage of own 16 cols (256 ch) ----
  // superstep: (chp, cg): 2x float4 (ch pair, 4 cols) -> 4 u32 LDS writes
  const float* xb = va + (size_t)b * 256 * 4096 + n0;
#pragma unroll
  for (int s = 0; s < 8; ++s) {
    int idx = s * 64 + lane;
    int cg = idx & 3;          // col group (4 cols)
    int chp = idx >> 2;        // channel pair 0..127
    const float* p = xb + (size_t)(2 * chp) * 4096 + wave * 16 + cg * 4;
    f32x4 fa = *(const f32x4*)p;
    f32x4 fb = *(const f32x4*)(p + 4096);
#pragma unroll
    for (int i = 0; i < 4; ++i)
      *(unsigned*)(Xs + (wave * 16 + cg * 4 + i) * PX + 2 * chp) = pk2(fa[i], fb[i]);
  }
  // no barrier: all Xs traffic below is wave-local.

  const int col = wave * 16 + ln;
  const size_t tok = (size_t)(b * 4096 + n0 + col);

  bhalf8 bx[8];
#pragma unroll
  for (int ks = 0; ks < 8; ++ks)
    bx[ks] = *(const bhalf8*)(Xs + col * PX + ks * 32 + quad * 8);

  f32x4 acc[8];
  // H = relu(Wa1 @ X) -> overlay into Xs (own cols; X consumed into bx)
#pragma unroll
  for (int rt = 0; rt < 8; ++rt) acc[rt] = (f32x4)(0.f);
#pragma unroll
  for (int rt = 0; rt < 8; ++rt)
#pragma unroll
    for (int ks = 0; ks < 8; ++ks) {
      bhalf8 af = *(const bhalf8*)((const short*)Wa1b + (rt * 16 + ln) * 256 + ks * 32 + quad * 8);
      acc[rt] = __builtin_amdgcn_mfma_f32_16x16x32_bf16(af, bx[ks], acc[rt], 0, 0, 0);
    }
#pragma unroll
  for (int rt = 0; rt < 8; ++rt) {
    f32x4 v = acc[rt];
    uint2 p;
    p.x = pk2(fmaxf(v.x, 0.f), fmaxf(v.y, 0.f));
    p.y = pk2(fmaxf(v.z, 0.f), fmaxf(v.w, 0.f));
    *(uint2*)(Xs + col * PX + rt * 16 + quad * 4) = p;
  }

  // gate_b = 1/(1+exp(Wgb @ X))
#pragma unroll
  for (int rt = 0; rt < 8; ++rt) acc[rt] = (f32x4)(0.f);
#pragma unroll
  for (int rt = 0; rt < 8; ++rt)
#pragma unroll
    for (int ks = 0; ks < 8; ++ks) {
      bhalf8 af = *(const bhalf8*)((const short*)Wgbb + (rt * 16 + ln) * 256 + ks * 32 + quad * 8);
      acc[rt] = __builtin_amdgcn_mfma_f32_16x16x32_bf16(af, bx[ks], acc[rt], 0, 0, 0);
    }
#pragma unroll
  for (int rt = 0; rt < 8; ++rt) {
    f32x4 v = acc[rt];
    uint2 p;
    p.x = pk2(1.f / (1.f + expf(v.x)), 1.f / (1.f + expf(v.y)));
    p.y = pk2(1.f / (1.f + expf(v.z)), 1.f / (1.f + expf(v.w)));
    *(uint2*)(Gb + tok * 128 + rt * 16 + quad * 4) = p;
  }

  // gate_c
#pragma unroll
  for (int rt = 0; rt < 8; ++rt) acc[rt] = (f32x4)(0.f);
#pragma unroll
  for (int rt = 0; rt < 8; ++rt)
#pragma unroll
    for (int ks = 0; ks < 8; ++ks) {
      bhalf8 af = *(const bhalf8*)((const short*)Wgcb + (rt * 16 + ln) * 256 + ks * 32 + quad * 8);
      acc[rt] = __builtin_amdgcn_mfma_f32_16x16x32_bf16(af, bx[ks], acc[rt], 0, 0, 0);
    }
#pragma unroll
  for (int rt = 0; rt < 8; ++rt) {
    f32x4 v = acc[rt];
    uint2 p;
    p.x = pk2(1.f / (1.f + expf(v.x)), 1.f / (1.f + expf(v.y)));
    p.y = pk2(1.f / (1.f + expf(v.z)), 1.f / (1.f + expf(v.w)));
    *(uint2*)(Gc + tok * 128 + rt * 16 + quad * 4) = p;
  }

  // E = Wa2 @ H (wave-local)
  bhalf8 bh[4];
#pragma unroll
  for (int ks = 0; ks < 4; ++ks)
    bh[ks] = *(const bhalf8*)(Xs + col * PX + ks * 32 + quad * 8);
#pragma unroll
  for (int rt = 0; rt < 8; ++rt) acc[rt] = (f32x4)(0.f);
#pragma unroll
  for (int rt = 0; rt < 8; ++rt)
#pragma unroll
    for (int ks = 0; ks < 4; ++ks) {
      bhalf8 af = *(const bhalf8*)((const short*)Wa2b + (rt * 16 + ln) * 128 + ks * 32 + quad * 8);
      acc[rt] = __builtin_amdgcn_mfma_f32_16x16x32_bf16(af, bh[ks], acc[rt], 0, 0, 0);
    }

  // proj + Sa = sigmoid(E)
  float pab = 0.f, pac = 0.f;
#pragma unroll
  for (int rt = 0; rt < 8; ++rt) {
    f32x4 v = acc[rt];
#pragma unroll
    for (int i = 0; i < 4; ++i) {
      float e = v[i];
      pab += wabl[rt * 16 + quad * 4 + i] * e;
      pac += wacl[rt * 16 + quad * 4 + i] * e;
    }
    uint2 p;
    p.x = pk2(1.f / (1.f + expf(-v.x)), 1.f / (1.f + expf(-v.y)));
    p.y = pk2(1.f / (1.f + expf(-v.z)), 1.f / (1.f + expf(-v.w)));
    *(uint2*)(Sa + tok * 128 + rt * 16 + quad * 4) = p;
  }
  pab += __shfl_xor(pab, 16, 64);
  pab += __shfl_xor(pab, 32, 64);
  pac += __shfl_xor(pac, 16, 64);
  pac += __shfl_xor(pac, 32, 64);
  if (lane < 16) {
    proj_ab[b * 4096 + n0 + col] = pab;
    proj_ac[b * 4096 + n0 + col] = pac;
  }
}

// ---------------------------------------------------------------------------
// MFMA attend body, fully wave-local, ZERO barriers.
// float4-vectorized staging; logit = extra MFMA rt-iter (W2ext row 128).
// W2b is [144][128] bf16: rows 0..127 = W2, row 128 = wv, rows 129.. = 0.
// ---------------------------------------------------------------------------
template <int R, int KIN>
__device__ __forceinline__ void attend_body(
    const float* __restrict__ vsrc,            // [B][KIN][64R][64R]
    const unsigned short* __restrict__ W1b,    // [128][KIN] bf16
    const unsigned short* __restrict__ W2b,    // [144][128] bf16 (ext)
    const float* __restrict__ proj,            // [B][4096]
    const unsigned short* __restrict__ gate,   // [B][4096][128] bf16
    unsigned short* __restrict__ outS,         // [B][4096][128] bf16
    unsigned short* smem, int blk) {
  constexpr int P = R * R;
  constexpr int T = 128 / P;   // tokens per block-pass
  constexpr int TW = 32 / P;   // tokens per wave
  constexpr int K1 = KIN / 32;
  constexpr int HR = 64 * R;
  constexpr int TILES = 4096 / T;

  const int u = threadIdx.x;
  const int b = blk / TILES;
  const int tile = blk % TILES;
  const int n0 = tile * T;
  const int h = n0 >> 6, w0 = n0 & 63;
  const size_t HRW = (size_t)HR * HR;
  const float* vb = vsrc + (size_t)b * KIN * HRW;

  const int wave = u >> 6, lane = u & 63, quad = lane >> 4, ln = lane & 15;
  const int tok0 = n0 + wave * TW;  // wave's first token (within image)

  // swizzled LDS address: row = col*256B, byte ^= (col&7)<<4 (involution)
  auto sa = [&](int col, int kshort) -> unsigned short* {
    unsigned byte = ((unsigned)col << 8) + ((unsigned)kshort << 1);
    byte ^= ((unsigned)(col & 7)) << 4;
    return (unsigned short*)((char*)smem + byte);
  };

  // ---- issue-early: proj (per c2 softmax group) + (R=4) gates ----
  float pa[2];
#pragma unroll
  for (int c2 = 0; c2 < 2; ++c2) {
    int twave = (c2 * 16) / P + (ln / P);  // token-within-wave for this lane
    pa[c2] = proj[b * 4096 + tok0 + twave];
  }
  unsigned gpre[TW <= 2 ? TW : 1];
  if constexpr (TW <= 2) {
#pragma unroll
    for (int t = 0; t < TW; ++t)
      gpre[t] = *(const unsigned*)(gate + ((size_t)b * 4096 + tok0 + t) * 128 + 2 * lane);
  }

  // ---- per-wave VECTORIZED stage of own 32 cols as bf16 [col][k] ----
  if constexpr (R == 4) {
    // KIN=64. float4 spans kw=0..3 of one (ch, kh, token).
#pragma unroll
    for (int s = 0; s < 4; ++s) {
      int idx = s * 64 + lane;
      int tl = idx & 1, kh = (idx >> 1) & 3, chp = idx >> 3;  // chp 0..31
      const float* p = vb + (size_t)(2 * chp) * HRW + (size_t)(h * 4 + kh) * HR
                       + (w0 + wave * 2 + tl) * 4;
      f32x4 fa = *(const f32x4*)p;
      f32x4 fb = *(const f32x4*)(p + HRW);
      int colb = wave * 32 + tl * 16 + kh * 4;
#pragma unroll
      for (int kw = 0; kw < 4; ++kw)
        *(unsigned*)sa(colb + kw, 2 * chp) = pk2(fa[kw], fb[kw]);
    }
  } else {
    // R==2, KIN=128. float4 spans (t,t+1)x(kw0,kw1) of one (ch, kh).
#pragma unroll
    for (int s = 0; s < 8; ++s) {
      int idx = s * 64 + lane;
      int tlp = idx & 3, kh = (idx >> 2) & 1, chp = idx >> 3;  // chp 0..63
      const float* p = vb + (size_t)(2 * chp) * HRW + (size_t)(h * 2 + kh) * HR
                       + (w0 + wave * 8 + tlp * 2) * 2;
      f32x4 fa = *(const f32x4*)p;
      f32x4 fb = *(const f32x4*)(p + HRW);
#pragma unroll
      for (int d = 0; d < 2; ++d)
#pragma unroll
        for (int kw = 0; kw < 2; ++kw) {
          int col = wave * 32 + (tlp * 2 + d) * 4 + kh * 2 + kw;
          *(unsigned*)sa(col, 2 * chp) = pk2(fa[d * 2 + kw], fb[d * 2 + kw]);
        }
    }
  }
  // no __syncthreads(): everything below is wave-local.

  // ---- layer 1: H = relu(W1 @ V) ----
  bhalf8 bf1[2][K1];
#pragma unroll
  for (int c2 = 0; c2 < 2; ++c2) {
    int col = wave * 32 + c2 * 16 + ln;
#pragma unroll
    for (int ks = 0; ks < K1; ++ks)
      bf1[c2][ks] = *(const bhalf8*)sa(col, ks * 32 + quad * 8);
  }
  f32x4 acc[8][2];
#pragma unroll
  for (int rt = 0; rt < 8; ++rt)
#pragma unroll
    for (int c2 = 0; c2 < 2; ++c2) acc[rt][c2] = (f32x4)(0.f);
#pragma unroll
  for (int rt = 0; rt < 8; ++rt) {
    bhalf8 af[K1];
#pragma unroll
    for (int ks = 0; ks < K1; ++ks)
      af[ks] = *(const bhalf8*)((const short*)W1b + (rt * 16 + ln) * KIN + ks * 32 + quad * 8);
#pragma unroll
    for (int c2 = 0; c2 < 2; ++c2)
#pragma unroll
      for (int ks = 0; ks < K1; ++ks)
        acc[rt][c2] = __builtin_amdgcn_mfma_f32_16x16x32_bf16(af[ks], bf1[c2][ks],
                                                              acc[rt][c2], 0, 0, 0);
  }
  // H overlay (own cols; V consumed into bf1)
#pragma unroll
  for (int rt = 0; rt < 8; ++rt)
#pragma unroll
    for (int c2 = 0; c2 < 2; ++c2) {
      int col = wave * 32 + c2 * 16 + ln;
      f32x4 v = acc[rt][c2];
      uint2 p;
      p.x = pk2(fmaxf(v.x, 0.f), fmaxf(v.y, 0.f));
      p.y = pk2(fmaxf(v.z, 0.f), fmaxf(v.w, 0.f));
      *(uint2*)sa(col, rt * 16 + quad * 4) = p;
    }

  // ---- layer 2: E = W2 @ H ----
  bhalf8 bf2[2][4];
#pragma unroll
  for (int c2 = 0; c2 < 2; ++c2) {
    int col = wave * 32 + c2 * 16 + ln;
#pragma unroll
    for (int ks = 0; ks < 4; ++ks)
      bf2[c2][ks] = *(const bhalf8*)sa(col, ks * 32 + quad * 8);
  }
#pragma unroll
  for (int rt = 0; rt < 8; ++rt)
#pragma unroll
    for (int c2 = 0; c2 < 2; ++c2) acc[rt][c2] = (f32x4)(0.f);
#pragma unroll
  for (int rt = 0; rt < 8; ++rt) {
    bhalf8 af[4];
#pragma unroll
    for (int ks = 0; ks < 4; ++ks)
      af[ks] = *(const bhalf8*)((const short*)W2b + (rt * 16 + ln) * 128 + ks * 32 + quad * 8);
#pragma unroll
    for (int c2 = 0; c2 < 2; ++c2)
#pragma unroll
      for (int ks = 0; ks < 4; ++ks)
        acc[rt][c2] = __builtin_amdgcn_mfma_f32_16x16x32_bf16(af[ks], bf2[c2][ks],
                                                              acc[rt][c2], 0, 0, 0);
  }

  // ---- logit via extra MFMA rt-iter: row 128 of W2ext = wv ----
  f32x4 acc9[2];
  acc9[0] = (f32x4)(0.f);
  acc9[1] = (f32x4)(0.f);
  {
    bhalf8 af[4];
#pragma unroll
    for (int ks = 0; ks < 4; ++ks)
      af[ks] = *(const bhalf8*)((const short*)W2b + (128 + ln) * 128 + ks * 32 + quad * 8);
#pragma unroll
    for (int c2 = 0; c2 < 2; ++c2)
#pragma unroll
      for (int ks = 0; ks < 4; ++ks)
        acc9[c2] = __builtin_amdgcn_mfma_f32_16x16x32_bf16(af[ks], bf2[c2][ks],
                                                           acc9[c2], 0, 0, 0);
  }

  // E overlay (own cols; H consumed into bf2)
#pragma unroll
  for (int rt = 0; rt < 8; ++rt)
#pragma unroll
    for (int c2 = 0; c2 < 2; ++c2) {
      int col = wave * 32 + c2 * 16 + ln;
      f32x4 v = acc[rt][c2];
      uint2 p;
      p.x = pk2(v.x, v.y);
      p.y = pk2(v.z, v.w);
      *(uint2*)sa(col, rt * 16 + quad * 4) = p;
    }

  // ---- softmax in MFMA layout: quad0 lanes hold logit of col c2*16+ln ----
  // valid on lanes 0..15 (quad==0); butterflies stay within the r-group.
  float wgt[2];
#pragma unroll
  for (int c2 = 0; c2 < 2; ++c2) {
    float lg = fmaxf(acc9[c2].x + pa[c2], 0.f);
    float mx = lg;
    mx = fmaxf(mx, __shfl_xor(mx, 1, 64));
    mx = fmaxf(mx, __shfl_xor(mx, 2, 64));
    if constexpr (P == 16) {
      mx = fmaxf(mx, __shfl_xor(mx, 4, 64));
      mx = fmaxf(mx, __shfl_xor(mx, 8, 64));
    }
    float ex = expf(lg - mx);
    float sm = ex;
    sm += __shfl_xor(sm, 1, 64);
    sm += __shfl_xor(sm, 2, 64);
    if constexpr (P == 16) {
      sm += __shfl_xor(sm, 4, 64);
      sm += __shfl_xor(sm, 8, 64);
    }
    wgt[c2] = ex / sm;  // weight of col c2*16+ln, valid on lanes 0..15
  }

  // ---- gated weighted sum + sigmoid -> token-major bf16 (own tokens) ----
#pragma unroll
  for (int t = 0; t < TW; ++t) {
    float s0 = 0.f, s1 = 0.f;
#pragma unroll
    for (int r = 0; r < P; ++r) {
      float w = __shfl(wgt[(t * P) >> 4], (t * P + r) & 15, 64);  // from quad0
      unsigned pkv = *(const unsigned*)sa(wave * 32 + t * P + r, 2 * lane);
      s0 += w * b2f((unsigned short)pkv);
      s1 += w * b2f((unsigned short)(pkv >> 16));
    }
    size_t tok = (size_t)b * 4096 + tok0 + t;
    unsigned gk;
    if constexpr (TW <= 2) gk = gpre[t];
    else gk = *(const unsigned*)(gate + tok * 128 + 2 * lane);
    float v0 = s0 * b2f((unsigned short)gk);
    float v1 = s1 * b2f((unsigned short)(gk >> 16));
    *(unsigned*)(outS + tok * 128 + 2 * lane) =
        pk2(1.f / (1.f + expf(-v0)), 1.f / (1.f + expf(-v1)));
  }
}

// ---------------------------------------------------------------------------
// Fused attend: both branches in one dispatch, 1:4 interleave.
// ---------------------------------------------------------------------------
__global__ __launch_bounds__(256) void k_attend_fused(
    const float* __restrict__ vb2, const unsigned short* __restrict__ W1b_b,
    const unsigned short* __restrict__ W2b_b,
    const float* __restrict__ proj_ab, const unsigned short* __restrict__ Gb,
    unsigned short* __restrict__ Sb,
    const float* __restrict__ vc4, const unsigned short* __restrict__ W1b_c,
    const unsigned short* __restrict__ W2b_c,
    const float* __restrict__ proj_ac, const unsigned short* __restrict__ Gc,
    unsigned short* __restrict__ Sc) {
  __shared__ unsigned short smem[128 * 128];  // exactly 32 KB -> 5 blocks/CU
  int bid = blockIdx.x;
  int g = bid / 5;
  int m = bid - g * 5;
  if (m == 0)
    attend_body<2, 128>(vb2, W1b_b, W2b_b, proj_ab, Gb, Sb, smem, g);
  else
    attend_body<4, 64>(vc4, W1b_c, W2b_c, proj_ac, Gc, Sc, smem,
                       g * 4 + (m - 1));
}

// ---------------------------------------------------------------------------
// Final (MFMA): S=[Sb|Sc|Sa] token-major bf16 (K=384); Y=relu(Wr1@S);
// out = Wr2 @ Y. 64 tokens/block, wave-local Y in LDS, no barriers.
// ---------------------------------------------------------------------------
__global__ __launch_bounds__(256) void k_final(
    const unsigned short* __restrict__ Sb, const unsigned short* __restrict__ Sc,
    const unsigned short* __restrict__ Sa,
    const unsigned short* __restrict__ Wr1b, const unsigned short* __restrict__ Wr2b,
    float* __restrict__ out) {
  constexpr int PY = 260;
  __shared__ unsigned short Ys[64 * PY];  // 33.3 KB
  const int u = threadIdx.x;
  const int b = blockIdx.x >> 6, tile = blockIdx.x & 63;
  const int n0 = tile * 64;
  const int wave = u >> 6, lane = u & 63, quad = lane >> 4, ln = lane & 15;
  const int col = wave * 16 + ln;
  const size_t tok = (size_t)(b * 4096 + n0 + col);

  bhalf8 bs[12];
#pragma unroll
  for (int ks = 0; ks < 12; ++ks) {
    const unsigned short* S = (ks < 4) ? Sb : ((ks < 8) ? Sc : Sa);
    bs[ks] = *(const bhalf8*)(S + tok * 128 + (ks & 3) * 32 + quad * 8);
  }

  f32x4 acc[16];
#pragma unroll
  for (int rt = 0; rt < 16; ++rt) acc[rt] = (f32x4)(0.f);
#pragma unroll
  for (int rt = 0; rt < 16; ++rt)
#pragma unroll
    for (int ks = 0; ks < 12; ++ks) {
      bhalf8 af = *(const bhalf8*)((const short*)Wr1b + (rt * 16 + ln) * 384 + ks * 32 + quad * 8);
      acc[rt] = __builtin_amdgcn_mfma_f32_16x16x32_bf16(af, bs[ks], acc[rt], 0, 0, 0);
    }
#pragma unroll
  for (int rt = 0; rt < 16; ++rt) {
    f32x4 v = acc[rt];
    uint2 p;
    p.x = pk2(fmaxf(v.x, 0.f), fmaxf(v.y, 0.f));
    p.y = pk2(fmaxf(v.z, 0.f), fmaxf(v.w, 0.f));
    *(uint2*)(Ys + col * PY + rt * 16 + quad * 4) = p;
  }

  // wave-local: no barrier needed
  bhalf8 by[8];
#pragma unroll
  for (int ks = 0; ks < 8; ++ks)
    by[ks] = *(const bhalf8*)(Ys + col * PY + ks * 32 + quad * 8);
#pragma unroll
  for (int rt = 0; rt < 16; ++rt) acc[rt] = (f32x4)(0.f);
#pragma unroll
  for (int rt = 0; rt < 16; ++rt)
#pragma unroll
    for (int ks = 0; ks < 8; ++ks) {
      bhalf8 af = *(const bhalf8*)((const short*)Wr2b + (rt * 16 + ln) * 256 + ks * 32 + quad * 8);
      acc[rt] = __builtin_amdgcn_mfma_f32_16x16x32_bf16(af, by[ks], acc[rt], 0, 0, 0);
    }
#pragma unroll
  for (int rt = 0; rt < 16; ++rt) {
    f32x4 v = acc[rt];
#pragma unroll
    for (int i = 0; i < 4; ++i)
      out[((size_t)(b * 256 + rt * 16 + quad * 4 + i)) * 4096 + n0 + col] = v[i];
  }
}

extern "C" void kernel_launch(void* const* d_in, const int* in_sizes, int n_in,
                              void* d_out, int out_size, void* d_ws, size_t ws_size,
                              hipStream_t stream) {
  (void)in_sizes; (void)n_in; (void)out_size; (void)ws_size;
  const float* va  = (const float*)d_in[0];
  const float* vb  = (const float*)d_in[1];
  const float* vc  = (const float*)d_in[2];
  const float* Wa1 = (const float*)d_in[3];
  const float* Wa2 = (const float*)d_in[4];
  const float* Wgb = (const float*)d_in[5];
  const float* Wgc = (const float*)d_in[6];
  const float* Wb1 = (const float*)d_in[7];
  const float* Wb2 = (const float*)d_in[8];
  const float* Wc1 = (const float*)d_in[9];
  const float* Wc2 = (const float*)d_in[10];
  const float* Wab = (const float*)d_in[11];
  const float* Wac = (const float*)d_in[12];
  const float* Wr1 = (const float*)d_in[13];
  const float* Wr2 = (const float*)d_in[14];
  float* out = (float*)d_out;
  float* f = (float*)d_ws;

  const size_t SM = (size_t)8 * 4096 * 128 / 2;  // bf16 token-major array, in floats
  unsigned short* Sb = (unsigned short*)f; f += SM;
  unsigned short* Sc = (unsigned short*)f; f += SM;
  unsigned short* Sa = (unsigned short*)f; f += SM;
  unsigned short* Gb = (unsigned short*)f; f += SM;
  unsigned short* Gc = (unsigned short*)f; f += SM;
  float* proj_ab = f; f += 8 * 4096;
  float* proj_ac = f; f += 8 * 4096;
  float* wv_b = f; f += 128;
  float* wv_c = f; f += 128;
  unsigned short* Wa1b = (unsigned short*)f; f += 16384;
  unsigned short* Wa2b = (unsigned short*)f; f += 8192;
  unsigned short* Wgbb = (unsigned short*)f; f += 16384;
  unsigned short* Wgcb = (unsigned short*)f; f += 16384;
  unsigned short* W1b_b = (unsigned short*)f; f += 8192;
  unsigned short* W2b_b = (unsigned short*)f; f += 9216;   // 144x128 ext
  unsigned short* W1b_c = (unsigned short*)f; f += 4096;
  unsigned short* W2b_c = (unsigned short*)f; f += 9216;   // 144x128 ext
  unsigned short* Wr1b = (unsigned short*)f; f += 49152;
  unsigned short* Wr2b = (unsigned short*)f; f += 32768;

  dim3 blk(256);
  k_prep_all<<<120, blk, 0, stream>>>(Wa1, Wa2, Wgb, Wgc, Wb1, Wb2, Wc1, Wc2,
                                      Wr1, Wr2, Wab, Wac,
                                      Wa1b, Wa2b, Wgbb, Wgcb, W1b_b, W2b_b,
                                      W1b_c, W2b_c, Wr1b, Wr2b, wv_b, wv_c);
  k_embA<<<512, blk, 0, stream>>>(va, Wa1b, Wa2b, Wgbb, Wgcb, Wab, Wac,
                                  Sa, Gb, Gc, proj_ab, proj_ac);
  k_attend_fused<<<5120, blk, 0, stream>>>(vb, W1b_b, W2b_b, proj_ab, Gb, Sb,
                                           vc, W1b_c, W2b_c, proj_ac, Gc, Sc);
  k_final<<<512, blk, 0, stream>>>(Sb, Sc, Sa, Wr1b, Wr2b, out);
}